// Round 3
// baseline (132.557 us; speedup 1.0000x reference)
//
#include <hip/hip_runtime.h>
#include <math.h>

#define BB 4
#define PP 24
#define NN 3072
#define SS 128
#define CHUNK 512
#define NSPLIT 6             // NN / CHUNK
#define PART_STRIDE 132      // 128 s-mins + pcl,cub,asum (+1 pad)

__device__ __forceinline__ float fexp_f(float v, float p) {
    float m = powf(fabsf(v), p);
    float s = (v > 0.f) ? 1.f : ((v < 0.f) ? -1.f : 0.f);
    return s * m;
}
__device__ __forceinline__ float fix_f(float v) {
    return ((v > 0.f) ? 1.f : -1.f) * fmaxf(fabsf(v), 1e-6f);
}
__device__ __forceinline__ float wave_sum(float v) {
    #pragma unroll
    for (int off = 32; off > 0; off >>= 1) v += __shfl_down(v, off);
    return v;
}
__device__ __forceinline__ float cub_dist(float px, float py, float pz,
                                          float nx, float ny, float nz,
                                          float sc0, float sc1, float sc2) {
    // argmax over {-nx,nx,-ny,ny,-nz,nz}; strict > == jnp first-max rule
    float best = -nx; int idx = 0;
    if ( nx > best) { best =  nx; idx = 1; }
    if (-ny > best) { best = -ny; idx = 2; }
    if ( ny > best) { best =  ny; idx = 3; }
    if (-nz > best) { best = -nz; idx = 4; }
    if ( nz > best) { best =  nz; idx = 5; }
    const int c = idx >> 1;
    const float scc = (c == 0) ? sc0 : ((c == 1) ? sc1 : sc2);
    const float fv  = (idx & 1) ? scc : -scc;
    float pr0 = (c == 0) ? fv : fminf(fmaxf(px, -sc0), sc0);
    float pr1 = (c == 1) ? fv : fminf(fmaxf(py, -sc1), sc1);
    float pr2 = (c == 2) ? fv : fminf(fmaxf(pz, -sc2), sc2);
    float d0 = pr0 - px, d1 = pr1 - py, d2 = pr2 - pz;
    return fmaf(d0, d0, fmaf(d1, d1, d2 * d2));
}

// ---- Kernel 1: main (96*NSPLIT=576 blocks x 256 threads, 2 points/thread) ----
__global__ __launch_bounds__(256) void superdec_main(
    const float* __restrict__ pc, const float* __restrict__ nrm,
    const float* __restrict__ scale, const float* __restrict__ shape,
    const float* __restrict__ assign,
    const float* __restrict__ etas, const float* __restrict__ omegas,
    float* __restrict__ ws)
{
    const int blk   = blockIdx.x;
    const int bp    = blk / NSPLIT;
    const int split = blk % NSPLIT;
    const int b     = bp / PP;
    const int p     = bp % PP;
    const int tid   = threadIdx.x;
    const int n0    = split * CHUNK;

    __shared__ float4 Xs[SS];       // (-2x, -2y, -2z, |x|^2)
    __shared__ float4 Pts[CHUNK];   // ( x,   y,   z,  |p|^2)
    __shared__ float  red[CHUNK];   // pass-B partial mins (4 quarters x 128 s)
    __shared__ float  wsum[12];

    const float sc0 = scale[bp * 3 + 0];
    const float sc1 = scale[bp * 3 + 1];
    const float sc2 = scale[bp * 3 + 2];

    // superquadric samples (redundant per split; powf cost negligible)
    if (tid < SS) {
        const float e1 = shape[bp * 2 + 0];
        const float e2 = shape[bp * 2 + 1];
        float eta = etas[bp * SS + tid];
        float omg = omegas[bp * SS + tid];
        eta = (eta == 0.f) ? 1e-6f : eta;
        omg = (omg == 0.f) ? 1e-6f : omg;
        float ce = cosf(eta), se = sinf(eta);
        float co = cosf(omg), so = sinf(omg);
        float fce = fexp_f(ce, e1);
        float x = fix_f(sc0 * fce * fexp_f(co, e2));
        float y = fix_f(sc1 * fce * fexp_f(so, e2));
        float z = fix_f(sc2 * fexp_f(se, e1));
        float xsq = fmaf(x, x, fmaf(y, y, z * z));
        Xs[tid] = make_float4(-2.f * x, -2.f * y, -2.f * z, xsq);
    }

    // this thread's two points
    const float* pcb = pc  + ((size_t)bp * NN + n0) * 3;
    const float* nrb = nrm + ((size_t)bp * NN + n0) * 3;
    const int iA = tid, iB = tid + 256;
    const float pxA = pcb[iA * 3 + 0], pyA = pcb[iA * 3 + 1], pzA = pcb[iA * 3 + 2];
    const float pxB = pcb[iB * 3 + 0], pyB = pcb[iB * 3 + 1], pzB = pcb[iB * 3 + 2];
    const float psqA = fmaf(pxA, pxA, fmaf(pyA, pyA, pzA * pzA));
    const float psqB = fmaf(pxB, pxB, fmaf(pyB, pyB, pzB * pzB));
    Pts[iA] = make_float4(pxA, pyA, pzA, psqA);
    Pts[iB] = make_float4(pxB, pyB, pzB, psqB);
    const float amA = assign[((size_t)b * NN + n0 + iA) * PP + p];
    const float amB = assign[((size_t)b * NN + n0 + iB) * PP + p];
    const float nxA = nrb[iA * 3 + 0], nyA = nrb[iA * 3 + 1], nzA = nrb[iA * 3 + 2];
    const float nxB = nrb[iB * 3 + 0], nyB = nrb[iB * 3 + 1], nzB = nrb[iB * 3 + 2];
    __syncthreads();

    // ---- Pass A: min over s for both points (d_eff = |x|^2 - 2x.p) ----
    float mA0 = 3.4e38f, mA1 = 3.4e38f, mB0 = 3.4e38f, mB1 = 3.4e38f;
    #pragma unroll 4
    for (int s = 0; s < SS; s += 2) {
        float4 x0 = Xs[s + 0];
        float4 x1 = Xs[s + 1];
        float d;
        d = fmaf(x0.x, pxA, fmaf(x0.y, pyA, fmaf(x0.z, pzA, x0.w))); mA0 = fminf(mA0, d);
        d = fmaf(x1.x, pxA, fmaf(x1.y, pyA, fmaf(x1.z, pzA, x1.w))); mA1 = fminf(mA1, d);
        d = fmaf(x0.x, pxB, fmaf(x0.y, pyB, fmaf(x0.z, pzB, x0.w))); mB0 = fminf(mB0, d);
        d = fmaf(x1.x, pxB, fmaf(x1.y, pyB, fmaf(x1.z, pzB, x1.w))); mB1 = fminf(mB1, d);
    }
    const float dminA = fminf(mA0, mA1) + psqA;
    const float dminB = fminf(mB0, mB1) + psqB;
    float acc_pcl = dminA * amA + dminB * amB;
    float acc_cub = cub_dist(pxA, pyA, pzA, nxA, nyA, nzA, sc0, sc1, sc2) * amA
                  + cub_dist(pxB, pyB, pzB, nxB, nyB, nzB, sc0, sc1, sc2) * amB;
    float acc_am  = amA + amB;

    {
        float s0 = wave_sum(acc_pcl);
        float s1 = wave_sum(acc_cub);
        float s2 = wave_sum(acc_am);
        const int lane = tid & 63, wave = tid >> 6;
        if (lane == 0) {
            wsum[wave * 3 + 0] = s0;
            wsum[wave * 3 + 1] = s1;
            wsum[wave * 3 + 2] = s2;
        }
    }

    // ---- Pass B: per-s min over this chunk; 2 s-values/thread, quarter of chunk ----
    {
        const int sA = tid & 63;
        const int q  = tid >> 6;            // wave-uniform
        const float4 xa = Xs[sA];
        const float4 xb = Xs[sA + 64];
        const int nb0 = q * (CHUNK / 4);    // 128 points per quarter
        float ma0 = 3.4e38f, ma1 = 3.4e38f, mb0 = 3.4e38f, mb1 = 3.4e38f;
        #pragma unroll 4
        for (int n = 0; n < CHUNK / 4; n += 2) {
            float4 p0 = Pts[nb0 + n];       // wave-uniform address -> broadcast
            float4 p1 = Pts[nb0 + n + 1];
            float d;
            d = fmaf(xa.x, p0.x, fmaf(xa.y, p0.y, fmaf(xa.z, p0.z, p0.w))); ma0 = fminf(ma0, d);
            d = fmaf(xa.x, p1.x, fmaf(xa.y, p1.y, fmaf(xa.z, p1.z, p1.w))); ma1 = fminf(ma1, d);
            d = fmaf(xb.x, p0.x, fmaf(xb.y, p0.y, fmaf(xb.z, p0.z, p0.w))); mb0 = fminf(mb0, d);
            d = fmaf(xb.x, p1.x, fmaf(xb.y, p1.y, fmaf(xb.z, p1.z, p1.w))); mb1 = fminf(mb1, d);
        }
        red[q * 128 + sA]      = fminf(ma0, ma1);   // d_eff2 = |p|^2 - 2x.p
        red[q * 128 + 64 + sA] = fminf(mb0, mb1);
    }
    __syncthreads();

    float* part = ws + (size_t)(bp * NSPLIT + split) * PART_STRIDE;
    if (tid < SS) {
        float m = fminf(fminf(red[tid], red[128 + tid]),
                        fminf(red[256 + tid], red[384 + tid]));
        part[tid] = m + Xs[tid].w;          // + |x_s|^2 -> true min distance
    }
    if (tid == 0) {
        part[SS + 0] = wsum[0] + wsum[3] + wsum[6] + wsum[9];
        part[SS + 1] = wsum[1] + wsum[4] + wsum[7] + wsum[10];
        part[SS + 2] = wsum[2] + wsum[5] + wsum[8] + wsum[11];
    }
}

// ---- Kernel 2: fused split-combine + final scalar (1 block x 1024 threads) ----
__global__ __launch_bounds__(1024) void superdec_reduce_final(
    const float* __restrict__ ws, const float* __restrict__ exist,
    float* __restrict__ out)
{
    __shared__ float s_prim[96], s_pcl[96], s_cub[96], s_sum[96];
    const int t    = threadIdx.x;
    const int lane = t & 63;
    if (t < 96) s_prim[t] = 0.f;
    __syncthreads();

    // per (bp,s): min over splits; wave covers 64 consecutive s of a single bp
    #pragma unroll
    for (int k = 0; k < (96 * 128) / 1024; ++k) {
        const int idx = t + k * 1024;
        const int bp  = idx >> 7;
        const int s   = idx & 127;
        const float* base = ws + (size_t)bp * (NSPLIT * PART_STRIDE) + s;
        float m = fminf(fminf(fminf(base[0 * PART_STRIDE], base[1 * PART_STRIDE]),
                              fminf(base[2 * PART_STRIDE], base[3 * PART_STRIDE])),
                        fminf(base[4 * PART_STRIDE], base[5 * PART_STRIDE]));
        float sm = wave_sum(m);             // bp uniform within wave
        if (lane == 0) atomicAdd(&s_prim[bp], sm);
    }
    if (t < 96 * 3) {
        const int bp = t / 3, v = t % 3;
        const float* base = ws + (size_t)bp * (NSPLIT * PART_STRIDE) + SS + v;
        float acc = 0.f;
        #pragma unroll
        for (int sp = 0; sp < NSPLIT; ++sp) acc += base[sp * PART_STRIDE];
        if      (v == 0) s_pcl[bp] = acc;
        else if (v == 1) s_cub[bp] = acc;
        else             s_sum[bp] = acc;
    }
    __syncthreads();

    if (t == 0) {
        float pcl_sum = 0.f, cub_sum = 0.f, bce_sum = 0.f, prim_loss = 0.f, sps = 0.f;
        for (int b_ = 0; b_ < BB; ++b_) {
            float pe = 0.f, ee = 0.f, sq = 0.f;
            for (int p_ = 0; p_ < PP; ++p_) {
                const int i = b_ * PP + p_;
                const float colsum = s_sum[i];
                const float e = exist[i];
                const float gt = (colsum > 24.0f) ? 1.f : 0.f;
                pcl_sum += s_pcl[i];
                cub_sum += s_cub[i];
                bce_sum += gt * logf(e) + (1.f - gt) * log1pf(-e);
                pe += (s_prim[i] / (float)SS) * e;
                ee += e;
                sq += sqrtf(colsum / (float)NN + 0.01f);
            }
            prim_loss += pe / (ee + 1e-6f);
            float mb = sq / (float)PP;
            sps += mb * mb;
        }
        prim_loss /= (float)BB;
        sps       /= (float)BB;
        float pcl_loss = pcl_sum / (float)(BB * NN);
        float cub      = cub_sum / (float)(BB * NN);
        float bce      = -bce_sum / (float)(BB * PP);
        out[0] = 0.1f * cub + 1.0f * (pcl_loss + prim_loss) + 0.01f * bce + 0.01f * sps;
    }
}

extern "C" void kernel_launch(void* const* d_in, const int* in_sizes, int n_in,
                              void* d_out, int out_size, void* d_ws, size_t ws_size,
                              hipStream_t stream) {
    const float* pc     = (const float*)d_in[0];
    const float* nrm    = (const float*)d_in[1];
    const float* scale  = (const float*)d_in[2];
    const float* shape  = (const float*)d_in[3];
    const float* exist  = (const float*)d_in[4];
    const float* assign = (const float*)d_in[5];
    const float* etas   = (const float*)d_in[6];
    const float* omegas = (const float*)d_in[7];
    float* ws  = (float*)d_ws;
    float* out = (float*)d_out;

    superdec_main<<<BB * PP * NSPLIT, 256, 0, stream>>>(
        pc, nrm, scale, shape, assign, etas, omegas, ws);
    superdec_reduce_final<<<1, 1024, 0, stream>>>(ws, exist, out);
}

// Round 4
// 95.536 us; speedup vs baseline: 1.3875x; 1.3875x over previous
//
#include <hip/hip_runtime.h>
#include <math.h>

#define BB 4
#define PP 24
#define NN 3072
#define SS 128
#define CHUNK 512
#define NSPLIT 6             // NN / CHUNK
#define PART_STRIDE 132      // 128 s-mins + pcl,cub,asum (+1 pad)

__device__ __forceinline__ float fexp_f(float v, float p) {
    float m = powf(fabsf(v), p);
    float s = (v > 0.f) ? 1.f : ((v < 0.f) ? -1.f : 0.f);
    return s * m;
}
__device__ __forceinline__ float fix_f(float v) {
    return ((v > 0.f) ? 1.f : -1.f) * fmaxf(fabsf(v), 1e-6f);
}
__device__ __forceinline__ float wave_sum(float v) {
    #pragma unroll
    for (int off = 32; off > 0; off >>= 1) v += __shfl_down(v, off);
    return v;
}
__device__ __forceinline__ float cub_dist(float px, float py, float pz,
                                          float nx, float ny, float nz,
                                          float sc0, float sc1, float sc2) {
    // argmax over {-nx,nx,-ny,ny,-nz,nz}; strict > == jnp first-max rule
    float best = -nx; int idx = 0;
    if ( nx > best) { best =  nx; idx = 1; }
    if (-ny > best) { best = -ny; idx = 2; }
    if ( ny > best) { best =  ny; idx = 3; }
    if (-nz > best) { best = -nz; idx = 4; }
    if ( nz > best) { best =  nz; idx = 5; }
    const int c = idx >> 1;
    const float scc = (c == 0) ? sc0 : ((c == 1) ? sc1 : sc2);
    const float fv  = (idx & 1) ? scc : -scc;
    float pr0 = (c == 0) ? fv : fminf(fmaxf(px, -sc0), sc0);
    float pr1 = (c == 1) ? fv : fminf(fmaxf(py, -sc1), sc1);
    float pr2 = (c == 2) ? fv : fminf(fmaxf(pz, -sc2), sc2);
    float d0 = pr0 - px, d1 = pr1 - py, d2 = pr2 - pz;
    return fmaf(d0, d0, fmaf(d1, d1, d2 * d2));
}

// ---- Kernel 1: main (96*NSPLIT=576 blocks x 256 threads, 2 points/thread) ----
__global__ __launch_bounds__(256) void superdec_main(
    const float* __restrict__ pc, const float* __restrict__ nrm,
    const float* __restrict__ scale, const float* __restrict__ shape,
    const float* __restrict__ assign,
    const float* __restrict__ etas, const float* __restrict__ omegas,
    float* __restrict__ ws)
{
    const int blk   = blockIdx.x;
    const int bp    = blk / NSPLIT;
    const int split = blk % NSPLIT;
    const int b     = bp / PP;
    const int p     = bp % PP;
    const int tid   = threadIdx.x;
    const int n0    = split * CHUNK;

    __shared__ float4 Xs[SS];       // (-2x, -2y, -2z, |x|^2)
    __shared__ float4 Pts[CHUNK];   // ( x,   y,   z,  |p|^2)
    __shared__ float  red[CHUNK];   // pass-B partial mins (4 quarters x 128 s)
    __shared__ float  wsum[12];

    const float sc0 = scale[bp * 3 + 0];
    const float sc1 = scale[bp * 3 + 1];
    const float sc2 = scale[bp * 3 + 2];

    // superquadric samples (redundant per split; powf cost negligible)
    if (tid < SS) {
        const float e1 = shape[bp * 2 + 0];
        const float e2 = shape[bp * 2 + 1];
        float eta = etas[bp * SS + tid];
        float omg = omegas[bp * SS + tid];
        eta = (eta == 0.f) ? 1e-6f : eta;
        omg = (omg == 0.f) ? 1e-6f : omg;
        float ce = cosf(eta), se = sinf(eta);
        float co = cosf(omg), so = sinf(omg);
        float fce = fexp_f(ce, e1);
        float x = fix_f(sc0 * fce * fexp_f(co, e2));
        float y = fix_f(sc1 * fce * fexp_f(so, e2));
        float z = fix_f(sc2 * fexp_f(se, e1));
        float xsq = fmaf(x, x, fmaf(y, y, z * z));
        Xs[tid] = make_float4(-2.f * x, -2.f * y, -2.f * z, xsq);
    }

    // this thread's two points
    const float* pcb = pc  + ((size_t)bp * NN + n0) * 3;
    const float* nrb = nrm + ((size_t)bp * NN + n0) * 3;
    const int iA = tid, iB = tid + 256;
    const float pxA = pcb[iA * 3 + 0], pyA = pcb[iA * 3 + 1], pzA = pcb[iA * 3 + 2];
    const float pxB = pcb[iB * 3 + 0], pyB = pcb[iB * 3 + 1], pzB = pcb[iB * 3 + 2];
    const float psqA = fmaf(pxA, pxA, fmaf(pyA, pyA, pzA * pzA));
    const float psqB = fmaf(pxB, pxB, fmaf(pyB, pyB, pzB * pzB));
    Pts[iA] = make_float4(pxA, pyA, pzA, psqA);
    Pts[iB] = make_float4(pxB, pyB, pzB, psqB);
    const float amA = assign[((size_t)b * NN + n0 + iA) * PP + p];
    const float amB = assign[((size_t)b * NN + n0 + iB) * PP + p];
    const float nxA = nrb[iA * 3 + 0], nyA = nrb[iA * 3 + 1], nzA = nrb[iA * 3 + 2];
    const float nxB = nrb[iB * 3 + 0], nyB = nrb[iB * 3 + 1], nzB = nrb[iB * 3 + 2];
    __syncthreads();

    // ---- Pass A: min over s for both points (d_eff = |x|^2 - 2x.p) ----
    float mA0 = 3.4e38f, mA1 = 3.4e38f, mB0 = 3.4e38f, mB1 = 3.4e38f;
    #pragma unroll 4
    for (int s = 0; s < SS; s += 2) {
        float4 x0 = Xs[s + 0];
        float4 x1 = Xs[s + 1];
        float d;
        d = fmaf(x0.x, pxA, fmaf(x0.y, pyA, fmaf(x0.z, pzA, x0.w))); mA0 = fminf(mA0, d);
        d = fmaf(x1.x, pxA, fmaf(x1.y, pyA, fmaf(x1.z, pzA, x1.w))); mA1 = fminf(mA1, d);
        d = fmaf(x0.x, pxB, fmaf(x0.y, pyB, fmaf(x0.z, pzB, x0.w))); mB0 = fminf(mB0, d);
        d = fmaf(x1.x, pxB, fmaf(x1.y, pyB, fmaf(x1.z, pzB, x1.w))); mB1 = fminf(mB1, d);
    }
    const float dminA = fminf(mA0, mA1) + psqA;
    const float dminB = fminf(mB0, mB1) + psqB;
    float acc_pcl = dminA * amA + dminB * amB;
    float acc_cub = cub_dist(pxA, pyA, pzA, nxA, nyA, nzA, sc0, sc1, sc2) * amA
                  + cub_dist(pxB, pyB, pzB, nxB, nyB, nzB, sc0, sc1, sc2) * amB;
    float acc_am  = amA + amB;

    {
        float s0 = wave_sum(acc_pcl);
        float s1 = wave_sum(acc_cub);
        float s2 = wave_sum(acc_am);
        const int lane = tid & 63, wave = tid >> 6;
        if (lane == 0) {
            wsum[wave * 3 + 0] = s0;
            wsum[wave * 3 + 1] = s1;
            wsum[wave * 3 + 2] = s2;
        }
    }

    // ---- Pass B: per-s min over this chunk; 2 s-values/thread, quarter of chunk ----
    {
        const int sA = tid & 63;
        const int q  = tid >> 6;            // wave-uniform
        const float4 xa = Xs[sA];
        const float4 xb = Xs[sA + 64];
        const int nb0 = q * (CHUNK / 4);    // 128 points per quarter
        float ma0 = 3.4e38f, ma1 = 3.4e38f, mb0 = 3.4e38f, mb1 = 3.4e38f;
        #pragma unroll 4
        for (int n = 0; n < CHUNK / 4; n += 2) {
            float4 p0 = Pts[nb0 + n];       // wave-uniform address -> broadcast
            float4 p1 = Pts[nb0 + n + 1];
            float d;
            d = fmaf(xa.x, p0.x, fmaf(xa.y, p0.y, fmaf(xa.z, p0.z, p0.w))); ma0 = fminf(ma0, d);
            d = fmaf(xa.x, p1.x, fmaf(xa.y, p1.y, fmaf(xa.z, p1.z, p1.w))); ma1 = fminf(ma1, d);
            d = fmaf(xb.x, p0.x, fmaf(xb.y, p0.y, fmaf(xb.z, p0.z, p0.w))); mb0 = fminf(mb0, d);
            d = fmaf(xb.x, p1.x, fmaf(xb.y, p1.y, fmaf(xb.z, p1.z, p1.w))); mb1 = fminf(mb1, d);
        }
        red[q * 128 + sA]      = fminf(ma0, ma1);   // d_eff2 = |p|^2 - 2x.p
        red[q * 128 + 64 + sA] = fminf(mb0, mb1);
    }
    __syncthreads();

    float* part = ws + (size_t)(bp * NSPLIT + split) * PART_STRIDE;
    if (tid < SS) {
        float m = fminf(fminf(red[tid], red[128 + tid]),
                        fminf(red[256 + tid], red[384 + tid]));
        part[tid] = m + Xs[tid].w;          // + |x_s|^2 -> true min distance
    }
    if (tid == 0) {
        part[SS + 0] = wsum[0] + wsum[3] + wsum[6] + wsum[9];
        part[SS + 1] = wsum[1] + wsum[4] + wsum[7] + wsum[10];
        part[SS + 2] = wsum[2] + wsum[5] + wsum[8] + wsum[11];
    }
}

// ---- Kernel 2: fused split-combine + final scalar (1 block x 1024 threads) ----
// All heavy-latency work (global loads, logf/sqrtf) done in PARALLEL threads;
// the t==0 epilogue touches only LDS.
__global__ __launch_bounds__(1024) void superdec_reduce_final(
    const float* __restrict__ ws, const float* __restrict__ exist,
    float* __restrict__ out)
{
    __shared__ float s_prim[96];   // sum over s of min-over-splits
    __shared__ float s_pcl[96], s_cub[96], s_bce[96], s_e[96], s_sq[96];
    const int t    = threadIdx.x;
    const int lane = t & 63;
    if (t < 96) s_prim[t] = 0.f;
    __syncthreads();

    // per (bp,s): min over splits; each wave covers 64 consecutive s of one bp
    #pragma unroll
    for (int k = 0; k < (96 * 128) / 1024; ++k) {
        const int idx = t + k * 1024;
        const int bp  = idx >> 7;
        const int s   = idx & 127;
        const float* base = ws + (size_t)bp * (NSPLIT * PART_STRIDE) + s;
        float m = fminf(fminf(fminf(base[0 * PART_STRIDE], base[1 * PART_STRIDE]),
                              fminf(base[2 * PART_STRIDE], base[3 * PART_STRIDE])),
                        fminf(base[4 * PART_STRIDE], base[5 * PART_STRIDE]));
        float sm = wave_sum(m);             // bp uniform within wave
        if (lane == 0) atomicAdd(&s_prim[bp], sm);
    }

    // parallel per-bp scalar terms (global loads + transcendentals hidden across 96 lanes)
    if (t < 96) {
        const float* base = ws + (size_t)t * (NSPLIT * PART_STRIDE) + SS;
        float pcl = 0.f, cub = 0.f, cs = 0.f;
        #pragma unroll
        for (int sp = 0; sp < NSPLIT; ++sp) {
            pcl += base[sp * PART_STRIDE + 0];
            cub += base[sp * PART_STRIDE + 1];
            cs  += base[sp * PART_STRIDE + 2];
        }
        const float e  = exist[t];
        const float gt = (cs > 24.0f) ? 1.f : 0.f;
        s_pcl[t] = pcl;
        s_cub[t] = cub;
        s_bce[t] = gt * logf(e) + (1.f - gt) * log1pf(-e);
        s_e[t]   = e;
        s_sq[t]  = sqrtf(cs / (float)NN + 0.01f);
    }
    __syncthreads();

    if (t == 0) {
        float pcl_sum = 0.f, cub_sum = 0.f, bce_sum = 0.f, prim_loss = 0.f, sps = 0.f;
        #pragma unroll
        for (int b_ = 0; b_ < BB; ++b_) {
            float pe = 0.f, ee = 0.f, sq = 0.f;
            #pragma unroll
            for (int p_ = 0; p_ < PP; ++p_) {
                const int i = b_ * PP + p_;
                pcl_sum += s_pcl[i];
                cub_sum += s_cub[i];
                bce_sum += s_bce[i];
                pe += (s_prim[i] / (float)SS) * s_e[i];
                ee += s_e[i];
                sq += s_sq[i];
            }
            prim_loss += pe / (ee + 1e-6f);
            float mb = sq / (float)PP;
            sps += mb * mb;
        }
        prim_loss /= (float)BB;
        sps       /= (float)BB;
        float pcl_loss = pcl_sum / (float)(BB * NN);
        float cub      = cub_sum / (float)(BB * NN);
        float bce      = -bce_sum / (float)(BB * PP);
        out[0] = 0.1f * cub + 1.0f * (pcl_loss + prim_loss) + 0.01f * bce + 0.01f * sps;
    }
}

extern "C" void kernel_launch(void* const* d_in, const int* in_sizes, int n_in,
                              void* d_out, int out_size, void* d_ws, size_t ws_size,
                              hipStream_t stream) {
    const float* pc     = (const float*)d_in[0];
    const float* nrm    = (const float*)d_in[1];
    const float* scale  = (const float*)d_in[2];
    const float* shape  = (const float*)d_in[3];
    const float* exist  = (const float*)d_in[4];
    const float* assign = (const float*)d_in[5];
    const float* etas   = (const float*)d_in[6];
    const float* omegas = (const float*)d_in[7];
    float* ws  = (float*)d_ws;
    float* out = (float*)d_out;

    superdec_main<<<BB * PP * NSPLIT, 256, 0, stream>>>(
        pc, nrm, scale, shape, assign, etas, omegas, ws);
    superdec_reduce_final<<<1, 1024, 0, stream>>>(ws, exist, out);
}

// Round 5
// 94.428 us; speedup vs baseline: 1.4038x; 1.0117x over previous
//
#include <hip/hip_runtime.h>
#include <math.h>

#define BB 4
#define PP 24
#define NN 3072
#define SS 128
#define CHUNK 512
#define NSPLIT 6             // NN / CHUNK
#define PART_STRIDE 132      // 128 s-mins + pcl,cub,asum (+1 pad)
#define FINF 3.4e38f

__device__ __forceinline__ float fexp_f(float v, float p) {
    float m = powf(fabsf(v), p);
    float s = (v > 0.f) ? 1.f : ((v < 0.f) ? -1.f : 0.f);
    return s * m;
}
__device__ __forceinline__ float fix_f(float v) {
    return ((v > 0.f) ? 1.f : -1.f) * fmaxf(fabsf(v), 1e-6f);
}
__device__ __forceinline__ float wave_sum(float v) {
    #pragma unroll
    for (int off = 32; off > 0; off >>= 1) v += __shfl_down(v, off);
    return v;
}
__device__ __forceinline__ float cub_dist(float px, float py, float pz,
                                          float nx, float ny, float nz,
                                          float sc0, float sc1, float sc2) {
    // argmax over {-nx,nx,-ny,ny,-nz,nz}; strict > == jnp first-max rule
    float best = -nx; int idx = 0;
    if ( nx > best) { best =  nx; idx = 1; }
    if (-ny > best) { best = -ny; idx = 2; }
    if ( ny > best) { best =  ny; idx = 3; }
    if (-nz > best) { best = -nz; idx = 4; }
    if ( nz > best) { best =  nz; idx = 5; }
    const int c = idx >> 1;
    const float scc = (c == 0) ? sc0 : ((c == 1) ? sc1 : sc2);
    const float fv  = (idx & 1) ? scc : -scc;
    float pr0 = (c == 0) ? fv : fminf(fmaxf(px, -sc0), sc0);
    float pr1 = (c == 1) ? fv : fminf(fmaxf(py, -sc1), sc1);
    float pr2 = (c == 2) ? fv : fminf(fmaxf(pz, -sc2), sc2);
    float d0 = pr0 - px, d1 = pr1 - py, d2 = pr2 - pz;
    return fmaf(d0, d0, fmaf(d1, d1, d2 * d2));
}

// ---- Kernel 1: main. 576 blocks x 256 threads. 4 points/thread, s-split halves.
__global__ __launch_bounds__(256) void superdec_main(
    const float* __restrict__ pc, const float* __restrict__ nrm,
    const float* __restrict__ scale, const float* __restrict__ shape,
    const float* __restrict__ assign,
    const float* __restrict__ etas, const float* __restrict__ omegas,
    float* __restrict__ ws)
{
    const int blk   = blockIdx.x;
    const int bp    = blk / NSPLIT;
    const int split = blk % NSPLIT;
    const int b     = bp / PP;
    const int p     = bp % PP;
    const int tid   = threadIdx.x;
    const int n0    = split * CHUNK;
    const int pid   = tid & 127;   // point-group id: points pid*4 .. pid*4+3
    const int q     = tid >> 7;    // s-half: 0 -> s[0,64), 1 -> s[64,128)

    __shared__ float4 Xs[SS];          // (-2x, -2y, -2z, |x|^2)
    __shared__ float4 Pts[CHUNK];      // ( x,   y,   z,  |p|^2)
    __shared__ float4 dmin2[2][128];   // per (half, pid): 4 per-point d_eff mins
    __shared__ float  red[8 * SS];     // pass-B replica mins
    __shared__ float  wsum[6];

    const float sc0 = scale[bp * 3 + 0];
    const float sc1 = scale[bp * 3 + 1];
    const float sc2 = scale[bp * 3 + 2];

    // ---- load this thread's 4 points via 3 contiguous float4 loads ----
    const float4* pc4 = (const float4*)(pc + ((size_t)bp * NN + n0) * 3);
    const float4 g0 = pc4[pid * 3 + 0];
    const float4 g1 = pc4[pid * 3 + 1];
    const float4 g2 = pc4[pid * 3 + 2];
    const float px0 = g0.x, py0 = g0.y, pz0 = g0.z;
    const float px1 = g0.w, py1 = g1.x, pz1 = g1.y;
    const float px2 = g1.z, py2 = g1.w, pz2 = g2.x;
    const float px3 = g2.y, py3 = g2.z, pz3 = g2.w;
    const float ps0 = fmaf(px0, px0, fmaf(py0, py0, pz0 * pz0));
    const float ps1 = fmaf(px1, px1, fmaf(py1, py1, pz1 * pz1));
    const float ps2 = fmaf(px2, px2, fmaf(py2, py2, pz2 * pz2));
    const float ps3 = fmaf(px3, px3, fmaf(py3, py3, pz3 * pz3));

    float cub0 = 0.f, cub1 = 0.f, cub2 = 0.f, cub3 = 0.f;
    float am0 = 0.f, am1 = 0.f, am2 = 0.f, am3 = 0.f;

    if (q == 0) {
        // superquadric samples (1 per thread)
        {
            const float e1 = shape[bp * 2 + 0];
            const float e2 = shape[bp * 2 + 1];
            float eta = etas[bp * SS + tid];
            float omg = omegas[bp * SS + tid];
            eta = (eta == 0.f) ? 1e-6f : eta;
            omg = (omg == 0.f) ? 1e-6f : omg;
            float ce = cosf(eta), se = sinf(eta);
            float co = cosf(omg), so = sinf(omg);
            float fce = fexp_f(ce, e1);
            float x = fix_f(sc0 * fce * fexp_f(co, e2));
            float y = fix_f(sc1 * fce * fexp_f(so, e2));
            float z = fix_f(sc2 * fexp_f(se, e1));
            float xsq = fmaf(x, x, fmaf(y, y, z * z));
            Xs[tid] = make_float4(-2.f * x, -2.f * y, -2.f * z, xsq);
        }
        // stage points for pass B
        Pts[pid * 4 + 0] = make_float4(px0, py0, pz0, ps0);
        Pts[pid * 4 + 1] = make_float4(px1, py1, pz1, ps1);
        Pts[pid * 4 + 2] = make_float4(px2, py2, pz2, ps2);
        Pts[pid * 4 + 3] = make_float4(px3, py3, pz3, ps3);
        // cuboid terms (normals used once; only half-0 loads them)
        const float4* nr4 = (const float4*)(nrm + ((size_t)bp * NN + n0) * 3);
        const float4 h0 = nr4[pid * 3 + 0];
        const float4 h1 = nr4[pid * 3 + 1];
        const float4 h2 = nr4[pid * 3 + 2];
        cub0 = cub_dist(px0, py0, pz0, h0.x, h0.y, h0.z, sc0, sc1, sc2);
        cub1 = cub_dist(px1, py1, pz1, h0.w, h1.x, h1.y, sc0, sc1, sc2);
        cub2 = cub_dist(px2, py2, pz2, h1.z, h1.w, h2.x, sc0, sc1, sc2);
        cub3 = cub_dist(px3, py3, pz3, h2.y, h2.z, h2.w, sc0, sc1, sc2);
        const size_t abase = ((size_t)b * NN + n0 + pid * 4) * PP + p;
        am0 = assign[abase + 0 * PP];
        am1 = assign[abase + 1 * PP];
        am2 = assign[abase + 2 * PP];
        am3 = assign[abase + 3 * PP];
    }
    __syncthreads();

    // ---- Pass A: min over this half's 64 s for 4 points (d_eff = |x|^2-2x.p) ----
    {
        const int sb = q * 64;
        float m0 = FINF, m1 = FINF, m2 = FINF, m3 = FINF;
        #pragma unroll 4
        for (int s = 0; s < 64; s += 2) {
            float4 xa = Xs[sb + s];
            float4 xb = Xs[sb + s + 1];
            float d;
            d = fmaf(xa.x, px0, fmaf(xa.y, py0, fmaf(xa.z, pz0, xa.w))); m0 = fminf(m0, d);
            d = fmaf(xa.x, px1, fmaf(xa.y, py1, fmaf(xa.z, pz1, xa.w))); m1 = fminf(m1, d);
            d = fmaf(xa.x, px2, fmaf(xa.y, py2, fmaf(xa.z, pz2, xa.w))); m2 = fminf(m2, d);
            d = fmaf(xa.x, px3, fmaf(xa.y, py3, fmaf(xa.z, pz3, xa.w))); m3 = fminf(m3, d);
            d = fmaf(xb.x, px0, fmaf(xb.y, py0, fmaf(xb.z, pz0, xb.w))); m0 = fminf(m0, d);
            d = fmaf(xb.x, px1, fmaf(xb.y, py1, fmaf(xb.z, pz1, xb.w))); m1 = fminf(m1, d);
            d = fmaf(xb.x, px2, fmaf(xb.y, py2, fmaf(xb.z, pz2, xb.w))); m2 = fminf(m2, d);
            d = fmaf(xb.x, px3, fmaf(xb.y, py3, fmaf(xb.z, pz3, xb.w))); m3 = fminf(m3, d);
        }
        dmin2[q][pid] = make_float4(m0, m1, m2, m3);
    }
    __syncthreads();

    // ---- half-0: combine s-halves, weight, wave-sum scalars ----
    if (q == 0) {
        float4 a = dmin2[0][pid];
        float4 c = dmin2[1][pid];
        float d0 = fminf(a.x, c.x) + ps0;
        float d1 = fminf(a.y, c.y) + ps1;
        float d2 = fminf(a.z, c.z) + ps2;
        float d3 = fminf(a.w, c.w) + ps3;
        float acc_pcl = d0 * am0 + d1 * am1 + d2 * am2 + d3 * am3;
        float acc_cub = cub0 * am0 + cub1 * am1 + cub2 * am2 + cub3 * am3;
        float acc_am  = am0 + am1 + am2 + am3;
        float s0 = wave_sum(acc_pcl);
        float s1 = wave_sum(acc_cub);
        float s2 = wave_sum(acc_am);
        const int lane = tid & 63, wave = tid >> 6;   // wave 0 or 1
        if (lane == 0) {
            wsum[wave * 3 + 0] = s0;
            wsum[wave * 3 + 1] = s1;
            wsum[wave * 3 + 2] = s2;
        }
    }

    // ---- Pass B: 4 s/thread, 8 point-replicas of 64 points each ----
    {
        const int rep = tid >> 5;     // 0..7
        const int sb  = tid & 31;
        const float4 x0 = Xs[sb];
        const float4 x1 = Xs[sb + 32];
        const float4 x2 = Xs[sb + 64];
        const float4 x3 = Xs[sb + 96];
        const int nb = rep * 64;
        float r0 = FINF, r1 = FINF, r2 = FINF, r3 = FINF;
        #pragma unroll 4
        for (int n = 0; n < 64; n += 2) {
            float4 pa = Pts[nb + n];
            float4 pb = Pts[nb + n + 1];
            float d;
            d = fmaf(x0.x, pa.x, fmaf(x0.y, pa.y, fmaf(x0.z, pa.z, pa.w))); r0 = fminf(r0, d);
            d = fmaf(x1.x, pa.x, fmaf(x1.y, pa.y, fmaf(x1.z, pa.z, pa.w))); r1 = fminf(r1, d);
            d = fmaf(x2.x, pa.x, fmaf(x2.y, pa.y, fmaf(x2.z, pa.z, pa.w))); r2 = fminf(r2, d);
            d = fmaf(x3.x, pa.x, fmaf(x3.y, pa.y, fmaf(x3.z, pa.z, pa.w))); r3 = fminf(r3, d);
            d = fmaf(x0.x, pb.x, fmaf(x0.y, pb.y, fmaf(x0.z, pb.z, pb.w))); r0 = fminf(r0, d);
            d = fmaf(x1.x, pb.x, fmaf(x1.y, pb.y, fmaf(x1.z, pb.z, pb.w))); r1 = fminf(r1, d);
            d = fmaf(x2.x, pb.x, fmaf(x2.y, pb.y, fmaf(x2.z, pb.z, pb.w))); r2 = fminf(r2, d);
            d = fmaf(x3.x, pb.x, fmaf(x3.y, pb.y, fmaf(x3.z, pb.z, pb.w))); r3 = fminf(r3, d);
        }
        red[rep * SS + sb +  0] = r0;   // d_eff2 = |p|^2 - 2x.p
        red[rep * SS + sb + 32] = r1;
        red[rep * SS + sb + 64] = r2;
        red[rep * SS + sb + 96] = r3;
    }
    __syncthreads();

    float* part = ws + (size_t)(bp * NSPLIT + split) * PART_STRIDE;
    if (tid < SS) {
        float m = red[tid];
        #pragma unroll
        for (int r = 1; r < 8; ++r) m = fminf(m, red[r * SS + tid]);
        part[tid] = m + Xs[tid].w;          // + |x_s|^2 -> true min distance
    }
    if (tid == 0) {
        part[SS + 0] = wsum[0] + wsum[3];
        part[SS + 1] = wsum[1] + wsum[4];
        part[SS + 2] = wsum[2] + wsum[5];
    }
}

// ---- Kernel 2: fused split-combine + final scalar (1 block x 1024 threads) ----
__global__ __launch_bounds__(1024) void superdec_reduce_final(
    const float* __restrict__ ws, const float* __restrict__ exist,
    float* __restrict__ out)
{
    __shared__ float s_prim[96];
    __shared__ float s_pcl[96], s_cub[96], s_bce[96], s_e[96], s_sq[96];
    const int t    = threadIdx.x;
    const int lane = t & 63;
    if (t < 96) s_prim[t] = 0.f;
    __syncthreads();

    // per (bp,s): min over splits; each wave covers 64 consecutive s of one bp
    #pragma unroll
    for (int k = 0; k < (96 * 128) / 1024; ++k) {
        const int idx = t + k * 1024;
        const int bp  = idx >> 7;
        const int s   = idx & 127;
        const float* base = ws + (size_t)bp * (NSPLIT * PART_STRIDE) + s;
        float m = fminf(fminf(fminf(base[0 * PART_STRIDE], base[1 * PART_STRIDE]),
                              fminf(base[2 * PART_STRIDE], base[3 * PART_STRIDE])),
                        fminf(base[4 * PART_STRIDE], base[5 * PART_STRIDE]));
        float sm = wave_sum(m);             // bp uniform within wave
        if (lane == 0) atomicAdd(&s_prim[bp], sm);
    }

    // parallel per-bp scalar terms
    if (t < 96) {
        const float* base = ws + (size_t)t * (NSPLIT * PART_STRIDE) + SS;
        float pcl = 0.f, cub = 0.f, cs = 0.f;
        #pragma unroll
        for (int sp = 0; sp < NSPLIT; ++sp) {
            pcl += base[sp * PART_STRIDE + 0];
            cub += base[sp * PART_STRIDE + 1];
            cs  += base[sp * PART_STRIDE + 2];
        }
        const float e  = exist[t];
        const float gt = (cs > 24.0f) ? 1.f : 0.f;
        s_pcl[t] = pcl;
        s_cub[t] = cub;
        s_bce[t] = gt * logf(e) + (1.f - gt) * log1pf(-e);
        s_e[t]   = e;
        s_sq[t]  = sqrtf(cs / (float)NN + 0.01f);
    }
    __syncthreads();

    if (t == 0) {
        float pcl_sum = 0.f, cub_sum = 0.f, bce_sum = 0.f, prim_loss = 0.f, sps = 0.f;
        #pragma unroll
        for (int b_ = 0; b_ < BB; ++b_) {
            float pe = 0.f, ee = 0.f, sq = 0.f;
            #pragma unroll
            for (int p_ = 0; p_ < PP; ++p_) {
                const int i = b_ * PP + p_;
                pcl_sum += s_pcl[i];
                cub_sum += s_cub[i];
                bce_sum += s_bce[i];
                pe += (s_prim[i] / (float)SS) * s_e[i];
                ee += s_e[i];
                sq += s_sq[i];
            }
            prim_loss += pe / (ee + 1e-6f);
            float mb = sq / (float)PP;
            sps += mb * mb;
        }
        prim_loss /= (float)BB;
        sps       /= (float)BB;
        float pcl_loss = pcl_sum / (float)(BB * NN);
        float cub      = cub_sum / (float)(BB * NN);
        float bce      = -bce_sum / (float)(BB * PP);
        out[0] = 0.1f * cub + 1.0f * (pcl_loss + prim_loss) + 0.01f * bce + 0.01f * sps;
    }
}

extern "C" void kernel_launch(void* const* d_in, const int* in_sizes, int n_in,
                              void* d_out, int out_size, void* d_ws, size_t ws_size,
                              hipStream_t stream) {
    const float* pc     = (const float*)d_in[0];
    const float* nrm    = (const float*)d_in[1];
    const float* scale  = (const float*)d_in[2];
    const float* shape  = (const float*)d_in[3];
    const float* exist  = (const float*)d_in[4];
    const float* assign = (const float*)d_in[5];
    const float* etas   = (const float*)d_in[6];
    const float* omegas = (const float*)d_in[7];
    float* ws  = (float*)d_ws;
    float* out = (float*)d_out;

    superdec_main<<<BB * PP * NSPLIT, 256, 0, stream>>>(
        pc, nrm, scale, shape, assign, etas, omegas, ws);
    superdec_reduce_final<<<1, 1024, 0, stream>>>(ws, exist, out);
}